// Round 5
// baseline (1252.201 us; speedup 1.0000x reference)
//
#include <hip/hip_runtime.h>

#define KDIM 512
#define TDIM 64
#define BDIM 256
#define NWAVE 16
#define BLOCK 1024
#define LOG2E 1.4426950408889634f

__device__ __forceinline__ float fast_exp2(float v) { return __builtin_amdgcn_exp2f(v); }
__device__ __forceinline__ float fast_rcp(float v)  { return __builtin_amdgcn_rcpf(v); }

// ---- prefold: b2 = bias * LOG2E (1 MB in d_ws; R4 proved d_ws is cached) ----
__global__ __launch_bounds__(256) void prefold_kernel(
    const float* __restrict__ bias, float* __restrict__ b2)
{
    const int i = blockIdx.x * 256 + threadIdx.x;   // float4 index
    const float4 b = ((const float4*)bias)[i];
    ((float4*)b2)[i] = make_float4(b.x * LOG2E, b.y * LOG2E, b.z * LOG2E, b.w * LOG2E);
}

__device__ __forceinline__ float wave_reduce_sum(float v) {
    #pragma unroll
    for (int off = 1; off < 64; off <<= 1)
        v += __shfl_xor(v, off, 64);
    return v;
}

// One workgroup per batch element; whole T-recurrence inside the kernel.
// R5 geometry: each transition row j is owned by a 16-lane GROUP (4 groups
// per wave -> 4 rows in flight), 32 elements per lane per row. Row-softmax
// butterfly is 4 hops over the group instead of 6 over the wave; per-t-step
// shfl count drops 192 -> 96. Register discipline per R2/R3 post-mortem:
// no deep manual prefetch, waves_per_eu(4,4) -> 128-VGPR budget.
template <bool FOLDED>
__global__ __launch_bounds__(BLOCK)
__attribute__((amdgpu_waves_per_eu(4, 4)))
void hmm_forward_kernel(
    const float* __restrict__ x,           // [B, T]
    const float* __restrict__ prior_w,     // [K]
    const float* __restrict__ emission_w,  // [K, 2]
    const float* __restrict__ coeff,       // [K, K]
    const float* __restrict__ bb,          // [K, K] = bias*LOG2E if FOLDED else bias
    float* __restrict__ out)               // [B, K]
{
    __shared__ float post[KDIM];
    __shared__ float em0s[KDIM];
    __shared__ float emds[KDIM];          // em1 - em0
    __shared__ float part[NWAVE][KDIM];   // per-wave pbe partials (32 KB)
    __shared__ float rtmp[NWAVE];
    __shared__ float xs[TDIM];

    const int b    = blockIdx.x;
    const int tid  = threadIdx.x;
    const int lane = tid & 63;
    const int wv   = tid >> 6;
    const int g    = lane >> 4;           // row group 0..3 within the wave
    const int l4   = lane & 15;           // lane within group

    if (tid < TDIM) xs[tid] = x[b * TDIM + tid];
    if (tid < KDIM) {
        const float w0 = emission_w[2 * tid + 0];
        const float w1 = emission_w[2 * tid + 1];
        const float e0 = 1.0f / (1.0f + fast_exp2((w1 - w0) * LOG2E));
        em0s[tid] = e0;
        emds[tid] = 1.0f - 2.0f * e0;
    }
    __syncthreads();

    // ---- t = 0 ----
    {
        const float x0 = xs[0];
        float v = 0.0f;
        if (tid < KDIM) {
            const float pr = fast_exp2(prior_w[tid] * LOG2E);
            v = pr * fmaf(x0, emds[tid], em0s[tid]);
        }
        float s = wave_reduce_sum(v);
        if (lane == 0) rtmp[wv] = s;
        __syncthreads();
        if (wv == 0) {
            float t2 = (lane < NWAVE) ? rtmp[lane] : 0.0f;
            #pragma unroll
            for (int off = 1; off < NWAVE; off <<= 1)
                t2 += __shfl_xor(t2, off, 64);
            if (lane == 0) rtmp[0] = t2;
        }
        __syncthreads();
        const float rn = fast_rcp(rtmp[0]);
        if (tid < KDIM) post[tid] = v * rn;
        __syncthreads();
    }

    // ---- steps t = 1 .. T-1 ----
    for (int t = 1; t < TDIM; ++t) {
        // lane's k-slots: k = l4*4 + m*64 + q  (m=0..7, q=0..3)
        float acc[8][4];
        #pragma unroll
        for (int m = 0; m < 8; ++m)
            #pragma unroll
            for (int q = 0; q < 4; ++q) acc[m][q] = 0.0f;

        #pragma unroll 1
        for (int i = 0; i < 8; ++i) {
            const int j = wv + NWAVE * (4 * i + g);   // this group's row
            const float p  = post[j];
            const float pL = FOLDED ? (p * LOG2E) : p;

            const float* crow = coeff + (size_t)j * KDIM + 4 * l4;
            const float* brow = bb    + (size_t)j * KDIM + 4 * l4;

            float e[8][4];
            float s8[8];
            #pragma unroll
            for (int m = 0; m < 8; ++m) {
                const float4 c  = *(const float4*)(crow + 64 * m);
                const float4 bq = *(const float4*)(brow + 64 * m);
                if (FOLDED) {
                    e[m][0] = fast_exp2(fmaf(pL, c.x, bq.x));
                    e[m][1] = fast_exp2(fmaf(pL, c.y, bq.y));
                    e[m][2] = fast_exp2(fmaf(pL, c.z, bq.z));
                    e[m][3] = fast_exp2(fmaf(pL, c.w, bq.w));
                } else {
                    e[m][0] = fast_exp2(fmaf(pL, c.x, bq.x) * LOG2E);
                    e[m][1] = fast_exp2(fmaf(pL, c.y, bq.y) * LOG2E);
                    e[m][2] = fast_exp2(fmaf(pL, c.z, bq.z) * LOG2E);
                    e[m][3] = fast_exp2(fmaf(pL, c.w, bq.w) * LOG2E);
                }
                s8[m] = (e[m][0] + e[m][1]) + (e[m][2] + e[m][3]);
            }

            float s = ((s8[0] + s8[1]) + (s8[2] + s8[3]))
                    + ((s8[4] + s8[5]) + (s8[6] + s8[7]));
            // 4-hop butterfly within the 16-lane group -> full row sum Z
            #pragma unroll
            for (int off = 1; off < 16; off <<= 1)
                s += __shfl_xor(s, off, 64);

            const float sc = p * fast_rcp(s);
            #pragma unroll
            for (int m = 0; m < 8; ++m) {
                acc[m][0] = fmaf(sc, e[m][0], acc[m][0]);
                acc[m][1] = fmaf(sc, e[m][1], acc[m][1]);
                acc[m][2] = fmaf(sc, e[m][2], acc[m][2]);
                acc[m][3] = fmaf(sc, e[m][3], acc[m][3]);
            }
        }

        // combine the 4 groups (same k-layout): 2-hop shfl per slot
        #pragma unroll
        for (int m = 0; m < 8; ++m) {
            #pragma unroll
            for (int q = 0; q < 4; ++q) {
                float v = acc[m][q];
                v += __shfl_xor(v, 16, 64);
                v += __shfl_xor(v, 32, 64);
                acc[m][q] = v;
            }
        }
        if (lane < 16) {
            #pragma unroll
            for (int m = 0; m < 8; ++m)
                *(float4*)(&part[wv][4 * l4 + 64 * m]) =
                    make_float4(acc[m][0], acc[m][1], acc[m][2], acc[m][3]);
        }
        __syncthreads();

        float v = 0.0f;
        if (tid < KDIM) {
            float pbe = 0.0f;
            #pragma unroll
            for (int w2 = 0; w2 < NWAVE; ++w2) pbe += part[w2][tid];
            v = pbe * fmaf(xs[t], emds[tid], em0s[tid]);
        }
        float s = wave_reduce_sum(v);
        if (lane == 0) rtmp[wv] = s;
        __syncthreads();
        if (wv == 0) {
            float t2 = (lane < NWAVE) ? rtmp[lane] : 0.0f;
            #pragma unroll
            for (int off = 1; off < NWAVE; off <<= 1)
                t2 += __shfl_xor(t2, off, 64);
            if (lane == 0) rtmp[0] = t2;
        }
        __syncthreads();
        const float rn = fast_rcp(rtmp[0]);
        if (tid < KDIM) post[tid] = v * rn;
        __syncthreads();
    }

    if (tid < KDIM) out[b * KDIM + tid] = post[tid];
}

extern "C" void kernel_launch(void* const* d_in, const int* in_sizes, int n_in,
                              void* d_out, int out_size, void* d_ws, size_t ws_size,
                              hipStream_t stream) {
    const float* x          = (const float*)d_in[0];
    const float* prior_w    = (const float*)d_in[1];
    const float* emission_w = (const float*)d_in[2];
    const float* coeff      = (const float*)d_in[3];
    const float* bias       = (const float*)d_in[4];
    float* out              = (float*)d_out;

    const size_t need = (size_t)KDIM * KDIM * sizeof(float);   // 1 MB for b2
    if (ws_size >= need) {
        float* b2 = (float*)d_ws;
        hipLaunchKernelGGL(prefold_kernel, dim3(KDIM * KDIM / 4 / 256), dim3(256),
                           0, stream, bias, b2);
        hipLaunchKernelGGL((hmm_forward_kernel<true>), dim3(BDIM), dim3(BLOCK),
                           0, stream, x, prior_w, emission_w, coeff, b2, out);
    } else {
        hipLaunchKernelGGL((hmm_forward_kernel<false>), dim3(BDIM), dim3(BLOCK),
                           0, stream, x, prior_w, emission_w, coeff, bias, out);
    }
}

// Round 6
// 1200.795 us; speedup vs baseline: 1.0428x; 1.0428x over previous
//
#include <hip/hip_runtime.h>

#define KDIM 512
#define TDIM 64
#define NWAVE 16
#define BLOCK 1024
#define LOG2E 1.4426950408889634f

// d_ws layout (float offsets):
//   [0, 256K)          b2 = bias*LOG2E (prefolded; R4 proved d_ws is cached)
//   [256K, 256K+512K)  exchange slots: (pair*2+writer)*2048 + parity*1024, each 1024 floats
//   [then]             flags: 256 ints (value = t; 0xAA poison is negative as int)
#define WS_B2     0
#define WS_XCHG   (KDIM * KDIM)
#define WS_FLAGS  (WS_XCHG + 128 * 2 * 2 * 1024)
#define WS_FLOATS (WS_FLAGS + 256)

__device__ __forceinline__ float fast_exp2(float v) { return __builtin_amdgcn_exp2f(v); }
__device__ __forceinline__ float fast_rcp(float v)  { return __builtin_amdgcn_rcpf(v); }

__global__ __launch_bounds__(256) void prefold_kernel(
    const float* __restrict__ bias, float* __restrict__ b2)
{
    const int i = blockIdx.x * 256 + threadIdx.x;
    const float4 b = ((const float4*)bias)[i];
    ((float4*)b2)[i] = make_float4(b.x * LOG2E, b.y * LOG2E, b.z * LOG2E, b.w * LOG2E);
}

__device__ __forceinline__ float wave_reduce_sum(float v) {
    #pragma unroll
    for (int off = 1; off < 64; off <<= 1)
        v += __shfl_xor(v, off, 64);
    return v;
}

// Pairwise row-split kernel: grid 256, 1 block/CU. Block gid: batches
// {gid&~1, gid|1}, rows [h*256,(h+1)*256) where h=gid&1. Halves per-CU L2
// matrix traffic (the R5-diagnosed bottleneck: 937us L2 floor at full
// stream). Per-step partial-pbe exchange with partner block via d_ws +
// agent-scope flag (monotone, poison-immune since (int)0xAAAAAAAA < 0).
__global__ __launch_bounds__(BLOCK)
__attribute__((amdgpu_waves_per_eu(4, 4)))
void hmm_pair_kernel(
    const float* __restrict__ x,           // [B, T]
    const float* __restrict__ prior_w,     // [K]
    const float* __restrict__ emission_w,  // [K, 2]
    const float* __restrict__ coeff,       // [K, K]
    float* __restrict__ ws,
    float* __restrict__ out)               // [B, K]
{
    __shared__ float post[2][KDIM];
    __shared__ float em0s[KDIM];
    __shared__ float emds[KDIM];
    __shared__ float part[NWAVE][2][KDIM];   // 64 KB
    __shared__ float rtmp[NWAVE];
    __shared__ float rn2[2];
    __shared__ float xs[2][TDIM];

    const int gid  = blockIdx.x;
    const int h    = gid & 1;              // row half
    const int pair = gid >> 1;
    const int b0   = gid & ~1;             // first batch of the pair
    const int tid  = threadIdx.x;
    const int lane = tid & 63;
    const int wv   = tid >> 6;
    const int k0   = 4 * lane;
    const int u    = tid >> 9;             // epilogue batch index
    const int k    = tid & 511;            // epilogue k index

    const float* bb = ws + WS_B2;
    int* flags   = (int*)(ws + WS_FLAGS);
    int* my_flag = flags + (pair * 2 + h);
    int* pr_flag = flags + (pair * 2 + (1 - h));
    float* my_slot = ws + WS_XCHG + (size_t)(pair * 2 + h) * 2048;
    float* pr_slot = ws + WS_XCHG + (size_t)(pair * 2 + (1 - h)) * 2048;

    if (tid < 2 * TDIM) xs[tid >> 6][tid & 63] = x[(b0 + (tid >> 6)) * TDIM + (tid & 63)];
    if (tid < KDIM) {
        const float w0 = emission_w[2 * tid + 0];
        const float w1 = emission_w[2 * tid + 1];
        const float e0 = 1.0f / (1.0f + fast_exp2((w1 - w0) * LOG2E));
        em0s[tid] = e0;
        emds[tid] = 1.0f - 2.0f * e0;
    }
    __syncthreads();

    // ---- t = 0: both batches, full K, locally ----
    {
        const float x0 = xs[u][0];
        const float pr = fast_exp2(prior_w[k] * LOG2E);
        float v = pr * fmaf(x0, emds[k], em0s[k]);
        float s = wave_reduce_sum(v);       // waves 0-7: batch0, 8-15: batch1
        if (lane == 0) rtmp[wv] = s;
        __syncthreads();
        if (wv < 2) {
            float t2 = (lane < 8) ? rtmp[wv * 8 + lane] : 0.0f;
            t2 += __shfl_xor(t2, 1, 64);
            t2 += __shfl_xor(t2, 2, 64);
            t2 += __shfl_xor(t2, 4, 64);
            if (lane == 0) rn2[wv] = fast_rcp(t2);
        }
        __syncthreads();
        post[u][k] = v * rn2[u];
        __syncthreads();
    }

    // ---- steps t = 1 .. T-1 ----
    for (int t = 1; t < TDIM; ++t) {
        float acc[2][8];
        #pragma unroll
        for (int uu = 0; uu < 2; ++uu)
            #pragma unroll
            for (int q = 0; q < 8; ++q) acc[uu][q] = 0.0f;

        // wave wv: row pairs (jA = h*256 + wv + 32*i, jB = jA + 16), i<8
        const float* cW = coeff + (size_t)(h * 256 + wv) * KDIM + k0;
        const float* bW = bb    + (size_t)(h * 256 + wv) * KDIM + k0;

        #pragma unroll 1
        for (int i = 0; i < 8; ++i) {
            const int jA = h * 256 + wv + 32 * i;
            const float* cA = cW + (size_t)(32 * i) * KDIM;
            const float* bA = bW + (size_t)(32 * i) * KDIM;
            const float* cB = cA + 16 * KDIM;
            const float* bB = bA + 16 * KDIM;
            const float4 cA0 = *(const float4*)cA;
            const float4 cA1 = *(const float4*)(cA + 256);
            const float4 bA0 = *(const float4*)bA;
            const float4 bA1 = *(const float4*)(bA + 256);
            const float4 cB0 = *(const float4*)cB;
            const float4 cB1 = *(const float4*)(cB + 256);
            const float4 bB0 = *(const float4*)bB;
            const float4 bB1 = *(const float4*)(bB + 256);

            #pragma unroll
            for (int uu = 0; uu < 2; ++uu) {
                const float pA  = post[uu][jA];
                const float pB  = post[uu][jA + 16];
                const float pAL = pA * LOG2E;
                const float pBL = pB * LOG2E;

                const float eA0 = fast_exp2(fmaf(pAL, cA0.x, bA0.x));
                const float eA1 = fast_exp2(fmaf(pAL, cA0.y, bA0.y));
                const float eA2 = fast_exp2(fmaf(pAL, cA0.z, bA0.z));
                const float eA3 = fast_exp2(fmaf(pAL, cA0.w, bA0.w));
                const float eA4 = fast_exp2(fmaf(pAL, cA1.x, bA1.x));
                const float eA5 = fast_exp2(fmaf(pAL, cA1.y, bA1.y));
                const float eA6 = fast_exp2(fmaf(pAL, cA1.z, bA1.z));
                const float eA7 = fast_exp2(fmaf(pAL, cA1.w, bA1.w));
                const float eB0 = fast_exp2(fmaf(pBL, cB0.x, bB0.x));
                const float eB1 = fast_exp2(fmaf(pBL, cB0.y, bB0.y));
                const float eB2 = fast_exp2(fmaf(pBL, cB0.z, bB0.z));
                const float eB3 = fast_exp2(fmaf(pBL, cB0.w, bB0.w));
                const float eB4 = fast_exp2(fmaf(pBL, cB1.x, bB1.x));
                const float eB5 = fast_exp2(fmaf(pBL, cB1.y, bB1.y));
                const float eB6 = fast_exp2(fmaf(pBL, cB1.z, bB1.z));
                const float eB7 = fast_exp2(fmaf(pBL, cB1.w, bB1.w));

                float sA = ((eA0 + eA1) + (eA2 + eA3)) + ((eA4 + eA5) + (eA6 + eA7));
                float sB = ((eB0 + eB1) + (eB2 + eB3)) + ((eB4 + eB5) + (eB6 + eB7));
                #pragma unroll
                for (int off = 1; off < 64; off <<= 1) {
                    sA += __shfl_xor(sA, off, 64);
                    sB += __shfl_xor(sB, off, 64);
                }
                const float scA = pA * fast_rcp(sA);
                const float scB = pB * fast_rcp(sB);

                acc[uu][0] = fmaf(scA, eA0, acc[uu][0]); acc[uu][0] = fmaf(scB, eB0, acc[uu][0]);
                acc[uu][1] = fmaf(scA, eA1, acc[uu][1]); acc[uu][1] = fmaf(scB, eB1, acc[uu][1]);
                acc[uu][2] = fmaf(scA, eA2, acc[uu][2]); acc[uu][2] = fmaf(scB, eB2, acc[uu][2]);
                acc[uu][3] = fmaf(scA, eA3, acc[uu][3]); acc[uu][3] = fmaf(scB, eB3, acc[uu][3]);
                acc[uu][4] = fmaf(scA, eA4, acc[uu][4]); acc[uu][4] = fmaf(scB, eB4, acc[uu][4]);
                acc[uu][5] = fmaf(scA, eA5, acc[uu][5]); acc[uu][5] = fmaf(scB, eB5, acc[uu][5]);
                acc[uu][6] = fmaf(scA, eA6, acc[uu][6]); acc[uu][6] = fmaf(scB, eB6, acc[uu][6]);
                acc[uu][7] = fmaf(scA, eA7, acc[uu][7]); acc[uu][7] = fmaf(scB, eB7, acc[uu][7]);
            }
        }

        *(float4*)(&part[wv][0][k0])       = make_float4(acc[0][0], acc[0][1], acc[0][2], acc[0][3]);
        *(float4*)(&part[wv][0][256 + k0]) = make_float4(acc[0][4], acc[0][5], acc[0][6], acc[0][7]);
        *(float4*)(&part[wv][1][k0])       = make_float4(acc[1][0], acc[1][1], acc[1][2], acc[1][3]);
        *(float4*)(&part[wv][1][256 + k0]) = make_float4(acc[1][4], acc[1][5], acc[1][6], acc[1][7]);
        __syncthreads();

        // half-pbe for (u, k); all 16 waves participate
        float pbe = 0.0f;
        #pragma unroll
        for (int w2 = 0; w2 < NWAVE; ++w2) pbe += part[w2][u][k];

        // exchange with partner (slot[tid] mapping == (u,k) mapping)
        float* slot = my_slot + (t & 1) * 1024;
        __hip_atomic_store(&slot[tid], pbe, __ATOMIC_RELAXED, __HIP_MEMORY_SCOPE_AGENT);
        __syncthreads();   // all waves drain vmcnt before barrier => stores visible
        if (tid == 0) {
            __hip_atomic_store(my_flag, t, __ATOMIC_RELEASE, __HIP_MEMORY_SCOPE_AGENT);
            int f = __hip_atomic_load(pr_flag, __ATOMIC_ACQUIRE, __HIP_MEMORY_SCOPE_AGENT);
            while (f < t) {
                __builtin_amdgcn_s_sleep(8);
                f = __hip_atomic_load(pr_flag, __ATOMIC_ACQUIRE, __HIP_MEMORY_SCOPE_AGENT);
            }
        }
        __syncthreads();
        const float* pslot = pr_slot + (t & 1) * 1024;
        const float other = __hip_atomic_load(&pslot[tid], __ATOMIC_RELAXED, __HIP_MEMORY_SCOPE_AGENT);

        float v = (pbe + other) * fmaf(xs[u][t], emds[k], em0s[k]);
        float s = wave_reduce_sum(v);
        if (lane == 0) rtmp[wv] = s;
        __syncthreads();
        if (wv < 2) {
            float t2 = (lane < 8) ? rtmp[wv * 8 + lane] : 0.0f;
            t2 += __shfl_xor(t2, 1, 64);
            t2 += __shfl_xor(t2, 2, 64);
            t2 += __shfl_xor(t2, 4, 64);
            if (lane == 0) rn2[wv] = fast_rcp(t2);
        }
        __syncthreads();
        post[u][k] = v * rn2[u];
        __syncthreads();
    }

    if (tid < KDIM) out[(size_t)gid * KDIM + tid] = post[h][tid];
}

// ---------- fallback: R4 single-batch kernel (no workspace needed) ----------
__global__ __launch_bounds__(BLOCK)
__attribute__((amdgpu_waves_per_eu(4, 4)))
void hmm_forward_kernel(
    const float* __restrict__ x, const float* __restrict__ prior_w,
    const float* __restrict__ emission_w, const float* __restrict__ coeff,
    const float* __restrict__ bias, float* __restrict__ out)
{
    __shared__ float post[KDIM];
    __shared__ float em0s[KDIM];
    __shared__ float emds[KDIM];
    __shared__ float part[NWAVE][KDIM];
    __shared__ float rtmp[NWAVE];
    __shared__ float xs[TDIM];

    const int b = blockIdx.x, tid = threadIdx.x, lane = tid & 63, wv = tid >> 6;
    const int k0 = 4 * lane;

    if (tid < TDIM) xs[tid] = x[b * TDIM + tid];
    if (tid < KDIM) {
        const float w0 = emission_w[2 * tid + 0];
        const float w1 = emission_w[2 * tid + 1];
        const float e0 = 1.0f / (1.0f + fast_exp2((w1 - w0) * LOG2E));
        em0s[tid] = e0;
        emds[tid] = 1.0f - 2.0f * e0;
    }
    __syncthreads();
    {
        const float x0 = xs[0];
        float v = 0.0f;
        if (tid < KDIM)
            v = fast_exp2(prior_w[tid] * LOG2E) * fmaf(x0, emds[tid], em0s[tid]);
        float s = wave_reduce_sum(v);
        if (lane == 0) rtmp[wv] = s;
        __syncthreads();
        if (wv == 0) {
            float t2 = (lane < NWAVE) ? rtmp[lane] : 0.0f;
            #pragma unroll
            for (int off = 1; off < NWAVE; off <<= 1) t2 += __shfl_xor(t2, off, 64);
            if (lane == 0) rtmp[0] = t2;
        }
        __syncthreads();
        const float rn = fast_rcp(rtmp[0]);
        if (tid < KDIM) post[tid] = v * rn;
        __syncthreads();
    }
    for (int t = 1; t < TDIM; ++t) {
        float acc[8];
        #pragma unroll
        for (int i = 0; i < 8; ++i) acc[i] = 0.0f;
        const float* cA = coeff + (size_t)wv * KDIM + k0;
        const float* bA = bias  + (size_t)wv * KDIM + k0;
        const float* cB = cA + 16 * KDIM;
        const float* bB = bA + 16 * KDIM;
        #pragma unroll 1
        for (int i = 0; i < 16; ++i) {
            const float4 cA0 = *(const float4*)cA;
            const float4 cA1 = *(const float4*)(cA + 256);
            const float4 cB0 = *(const float4*)cB;
            const float4 cB1 = *(const float4*)(cB + 256);
            const float4 bA0 = *(const float4*)bA;
            const float4 bA1 = *(const float4*)(bA + 256);
            const float4 bB0 = *(const float4*)bB;
            const float4 bB1 = *(const float4*)(bB + 256);
            cA += 32 * KDIM; cB += 32 * KDIM; bA += 32 * KDIM; bB += 32 * KDIM;
            const float pA = post[wv + 32 * i];
            const float pB = post[wv + 16 + 32 * i];
            const float eA0 = fast_exp2(fmaf(pA, cA0.x, bA0.x) * LOG2E);
            const float eA1 = fast_exp2(fmaf(pA, cA0.y, bA0.y) * LOG2E);
            const float eA2 = fast_exp2(fmaf(pA, cA0.z, bA0.z) * LOG2E);
            const float eA3 = fast_exp2(fmaf(pA, cA0.w, bA0.w) * LOG2E);
            const float eA4 = fast_exp2(fmaf(pA, cA1.x, bA1.x) * LOG2E);
            const float eA5 = fast_exp2(fmaf(pA, cA1.y, bA1.y) * LOG2E);
            const float eA6 = fast_exp2(fmaf(pA, cA1.z, bA1.z) * LOG2E);
            const float eA7 = fast_exp2(fmaf(pA, cA1.w, bA1.w) * LOG2E);
            const float eB0 = fast_exp2(fmaf(pB, cB0.x, bB0.x) * LOG2E);
            const float eB1 = fast_exp2(fmaf(pB, cB0.y, bB0.y) * LOG2E);
            const float eB2 = fast_exp2(fmaf(pB, cB0.z, bB0.z) * LOG2E);
            const float eB3 = fast_exp2(fmaf(pB, cB0.w, bB0.w) * LOG2E);
            const float eB4 = fast_exp2(fmaf(pB, cB1.x, bB1.x) * LOG2E);
            const float eB5 = fast_exp2(fmaf(pB, cB1.y, bB1.y) * LOG2E);
            const float eB6 = fast_exp2(fmaf(pB, cB1.z, bB1.z) * LOG2E);
            const float eB7 = fast_exp2(fmaf(pB, cB1.w, bB1.w) * LOG2E);
            float sA = ((eA0 + eA1) + (eA2 + eA3)) + ((eA4 + eA5) + (eA6 + eA7));
            float sB = ((eB0 + eB1) + (eB2 + eB3)) + ((eB4 + eB5) + (eB6 + eB7));
            #pragma unroll
            for (int off = 1; off < 64; off <<= 1) {
                sA += __shfl_xor(sA, off, 64);
                sB += __shfl_xor(sB, off, 64);
            }
            const float scA = pA * fast_rcp(sA);
            const float scB = pB * fast_rcp(sB);
            acc[0] = fmaf(scA, eA0, acc[0]); acc[0] = fmaf(scB, eB0, acc[0]);
            acc[1] = fmaf(scA, eA1, acc[1]); acc[1] = fmaf(scB, eB1, acc[1]);
            acc[2] = fmaf(scA, eA2, acc[2]); acc[2] = fmaf(scB, eB2, acc[2]);
            acc[3] = fmaf(scA, eA3, acc[3]); acc[3] = fmaf(scB, eB3, acc[3]);
            acc[4] = fmaf(scA, eA4, acc[4]); acc[4] = fmaf(scB, eB4, acc[4]);
            acc[5] = fmaf(scA, eA5, acc[5]); acc[5] = fmaf(scB, eB5, acc[5]);
            acc[6] = fmaf(scA, eA6, acc[6]); acc[6] = fmaf(scB, eB6, acc[6]);
            acc[7] = fmaf(scA, eA7, acc[7]); acc[7] = fmaf(scB, eB7, acc[7]);
        }
        *(float4*)(&part[wv][k0])       = make_float4(acc[0], acc[1], acc[2], acc[3]);
        *(float4*)(&part[wv][256 + k0]) = make_float4(acc[4], acc[5], acc[6], acc[7]);
        __syncthreads();
        float v = 0.0f;
        if (tid < KDIM) {
            float pbe = 0.0f;
            #pragma unroll
            for (int w2 = 0; w2 < NWAVE; ++w2) pbe += part[w2][tid];
            v = pbe * fmaf(xs[t], emds[tid], em0s[tid]);
        }
        float s = wave_reduce_sum(v);
        if (lane == 0) rtmp[wv] = s;
        __syncthreads();
        if (wv == 0) {
            float t2 = (lane < NWAVE) ? rtmp[lane] : 0.0f;
            #pragma unroll
            for (int off = 1; off < NWAVE; off <<= 1) t2 += __shfl_xor(t2, off, 64);
            if (lane == 0) rtmp[0] = t2;
        }
        __syncthreads();
        const float rn = fast_rcp(rtmp[0]);
        if (tid < KDIM) post[tid] = v * rn;
        __syncthreads();
    }
    if (tid < KDIM) out[b * KDIM + tid] = post[tid];
}

extern "C" void kernel_launch(void* const* d_in, const int* in_sizes, int n_in,
                              void* d_out, int out_size, void* d_ws, size_t ws_size,
                              hipStream_t stream) {
    const float* x          = (const float*)d_in[0];
    const float* prior_w    = (const float*)d_in[1];
    const float* emission_w = (const float*)d_in[2];
    const float* coeff      = (const float*)d_in[3];
    const float* bias       = (const float*)d_in[4];
    float* out              = (float*)d_out;

    if (ws_size >= (size_t)WS_FLOATS * sizeof(float)) {
        float* ws = (float*)d_ws;
        hipLaunchKernelGGL(prefold_kernel, dim3(KDIM * KDIM / 4 / 256), dim3(256),
                           0, stream, bias, ws + WS_B2);
        hipLaunchKernelGGL(hmm_pair_kernel, dim3(256), dim3(BLOCK), 0, stream,
                           x, prior_w, emission_w, coeff, ws, out);
    } else {
        hipLaunchKernelGGL(hmm_forward_kernel, dim3(256), dim3(BLOCK), 0, stream,
                           x, prior_w, emission_w, coeff, bias, out);
    }
}